// Round 7
// baseline (221.893 us; speedup 1.0000x reference)
//
#include <hip/hip_runtime.h>
#include <stdint.h>

#define PRIME 1000003u
#define NORD  1000002u
#define KCH   16
#define BATCH 4
#define NPATCH 784
#define LLEN  9
#define IPMAX 9000          // |<x,y>| <= 20*50*9
#define TBLN  (2*IPMAX+1)

// Workspace layout (bytes); ws is 256 MiB, we use ~2 MB.
//   [0,       2000006)  int16 dlog table (p entries)
//   [2000128, 2050304)  float pooled [4][16][14][14]
#define POOL_OFF 2000128

// Barrett: M = floor(2^41/p) = 2199016; exact for t < 2^40 with one cond-sub.
__device__ __forceinline__ uint32_t mmul(uint32_t a, uint32_t b) {
    uint64_t t = (uint64_t)a * (uint64_t)b;
    uint32_t q = (uint32_t)((t * 2199016ull) >> 41);
    uint32_t r = (uint32_t)t - q * PRIME;
    return (r >= PRIME) ? r - PRIME : r;
}

__device__ __forceinline__ uint32_t mpow(uint32_t base, uint32_t exp) {
    uint32_t r = 1u, b = base;
    while (exp) {
        if (exp & 1u) r = mmul(r, b);
        b = mmul(b, b);
        exp >>= 1;
    }
    return r;
}

// ---------------- Kernel 1: dlog lookup table (int16) -----------------------
// table[g^e mod p] = e for e in [-9000,9000]. Only queried entries are ever
// written (decrypted values are guaranteed g^e).
__global__ void build_table(const int* __restrict__ g_in, int16_t* __restrict__ table) {
    int e = blockIdx.x * blockDim.x + threadIdx.x;
    if (e >= TBLN) return;
    int es = e - IPMAX;
    uint32_t exp = (es >= 0) ? (uint32_t)es : (uint32_t)(es + (int)NORD);
    table[mpow((uint32_t)g_in[0], exp)] = (int16_t)es;
}

// ---------------- Kernel 2: decrypt + bn1 + relu + pool(28->14) -------------
// 128 blocks x 448 threads; block = (k, b, half: 14 rows = 392 patches).
// k/b/sk/y-row/bn1 params are block-uniform -> scalar. Plain stores; the
// kernel boundary provides cross-kernel visibility (no atomics anywhere).
__global__ void __launch_bounds__(448) decrypt_pool(
    const int* __restrict__ ct0, const int* __restrict__ cts,
    const int* __restrict__ y, const int* __restrict__ sk_y,
    const float* __restrict__ bias1,
    const float* __restrict__ bn1_g, const float* __restrict__ bn1_b,
    const float* __restrict__ bn1_m, const float* __restrict__ bn1_v,
    const int16_t* __restrict__ table, float* __restrict__ pooled) {
    __shared__ float raw[392];                 // 14 rows x 28 cols
    const int bid = blockIdx.x, tid = threadIdx.x;
    const int pair = bid >> 1, half = bid & 1;
    const int k = pair & 15, b = pair >> 4;

    const int* yrow = y + k * LLEN;
    int yv[LLEN];
#pragma unroll
    for (int i = 0; i < LLEN; i++) yv[i] = yrow[i];          // scalar loads
    const uint32_t sk = (uint32_t)sk_y[k];
    const float sc  = bn1_g[k] * rsqrtf(bn1_v[k] + 1e-5f);
    const float shf = (bias1[k] - bn1_m[k]) * sc + bn1_b[k];

    if (tid < 392) {
        const int j = half * 392 + tid;
        const int* crow = cts + ((b * NPATCH) + j) * LLEN;
        uint32_t c[LLEN];
#pragma unroll
        for (int i = 0; i < LLEN; i++) c[i] = (uint32_t)crow[i];

        // Shamir: |y_i| <= 50 < 64 (6 bits). Branch conds block-uniform.
        uint32_t accp = 1u, accn = 1u;
#pragma unroll
        for (int bit = 5; bit >= 0; bit--) {
            accp = mmul(accp, accp);
            accn = mmul(accn, accn);
#pragma unroll
            for (int i = 0; i < LLEN; i++) {
                int yi = yv[i];
                int ay = (yi > 0) ? yi : -yi;
                if ((ay >> bit) & 1) {
                    if (yi > 0) accp = mmul(accp, c[i]);
                    else        accn = mmul(accn, c[i]);
                }
            }
        }

        uint32_t den = mmul(mpow((uint32_t)ct0[b * NPATCH + j], sk), accn);
        uint32_t val = mmul(accp, mpow(den, PRIME - 2u));    // const exp: unrolls

        int ip = (int)table[val];              // guaranteed hit, |ip|<=9000
        raw[tid] = fmaxf(fmaf((float)ip, sc * 1e-4f, shf), 0.0f);
    }
    __syncthreads();
    if (tid < 98) {                            // pool 14x28 -> 7x14
        int pyl = tid / 14, px = tid % 14;
        const float* r0 = &raw[(2 * pyl) * 28 + 2 * px];
        float m = fmaxf(fmaxf(r0[0], r0[1]), fmaxf(r0[28], r0[29]));
        pooled[((b * KCH) + k) * 196 + (half * 7 + pyl) * 14 + px] = m;
    }
}

// ---------------- Kernel 3: conv2+conv3+fc, one block per batch -------------
// All post-decrypt dependencies are per-batch, so a single 1024-thread block
// per batch needs only __syncthreads (no grid sync, no global intermediates:
// s2p and s3 stay in LDS). ~1.9M MAC/block on one CU ~= 8us wall, cheaper
// than any measured grid-barrier chain (~10-15us per handoff, r2-r6).
__global__ void __launch_bounds__(1024) convnet(
    const float* __restrict__ pooled,
    const float* __restrict__ conv2_w, const float* __restrict__ conv2_b,
    const float* __restrict__ bn2_g, const float* __restrict__ bn2_b,
    const float* __restrict__ bn2_m, const float* __restrict__ bn2_v,
    const float* __restrict__ conv3_w, const float* __restrict__ conv3_b,
    const float* __restrict__ bn3_g, const float* __restrict__ bn3_b,
    const float* __restrict__ bn3_m, const float* __restrict__ bn3_v,
    const float* __restrict__ fc1_w, const float* __restrict__ fc1_b,
    const float* __restrict__ fc2_w, const float* __restrict__ fc2_b,
    float* __restrict__ out) {
    const int b = blockIdx.x, tid = threadIdx.x;

    __shared__ float s2p[32][9][9];            // 10.4 KB, persists conv2->conv3
    __shared__ float s3[576];                  // 2.3 KB,  persists conv3->fc
    __shared__ union {
        struct { float s1p[16][16][16]; float w2[32 * 144]; float co[4][196]; } a; // 38 KB
        struct { float w3[16 * 288]; float co3[16][49]; } c;                       // 21.6 KB
        struct { float h[128]; } d;
    } sm;                                      // total static LDS ~50.6 KB

    // ---- stage 0: zero halos, stage conv2 weights + pooled input ----------
    for (int i = tid; i < 16 * 16 * 16; i += 1024) ((float*)sm.a.s1p)[i] = 0.0f;
    for (int i = tid; i < 32 * 81;      i += 1024) ((float*)s2p)[i] = 0.0f;
    for (int i = tid; i < 32 * 144;     i += 1024) sm.a.w2[i] = conv2_w[i];
    __syncthreads();
    for (int i = tid; i < 16 * 196; i += 1024) {
        int ic = i / 196, pos = i % 196;
        sm.a.s1p[ic][pos / 14 + 1][pos % 14 + 1] = pooled[(b * KCH + ic) * 196 + pos];
    }
    __syncthreads();

    // ---- conv2 + bn2 + relu + pool(14->7): 8 passes x 4 oc ----------------
    for (int g = 0; g < 8; ++g) {
        if (tid < 784) {
            int ocs = tid / 196, pos = tid % 196;
            int oh = pos / 14, ow = pos % 14;
            int oc = g * 4 + ocs;
            float a0 = 0.0f, a1 = 0.0f, a2 = 0.0f;
#pragma unroll
            for (int ic = 0; ic < 16; ic++) {
                const float* wp = &sm.a.w2[oc * 144 + ic * 9];
                const float* sp = &sm.a.s1p[ic][oh][ow];
                a0 = fmaf(sp[0],  wp[0], fmaf(sp[1],  wp[1], fmaf(sp[2],  wp[2], a0)));
                a1 = fmaf(sp[16], wp[3], fmaf(sp[17], wp[4], fmaf(sp[18], wp[5], a1)));
                a2 = fmaf(sp[32], wp[6], fmaf(sp[33], wp[7], fmaf(sp[34], wp[8], a2)));
            }
            float sc = bn2_g[oc] * rsqrtf(bn2_v[oc] + 1e-5f);
            float shf = bn2_b[oc] - bn2_m[oc] * sc;
            sm.a.co[ocs][pos] = fmaxf((a0 + a1 + a2 + conv2_b[oc]) * sc + shf, 0.0f);
        }
        __syncthreads();
        if (tid < 196) {                       // 4 oc x 49 pooled outputs
            int ocs = tid / 49, pp = tid % 49;
            int oh = pp / 7, ow = pp % 7;
            const float* c0 = &sm.a.co[ocs][(2 * oh) * 14 + 2 * ow];
            s2p[g * 4 + ocs][oh + 1][ow + 1] =
                fmaxf(fmaxf(c0[0], c0[1]), fmaxf(c0[14], c0[15]));
        }
        __syncthreads();                       // co reused next pass
    }

    // ---- conv3 + bn3 + relu + pool(7->3): 4 passes x 16 oc ----------------
    for (int g = 0; g < 4; ++g) {
        for (int i = tid; i < 16 * 288; i += 1024)
            sm.c.w3[i] = conv3_w[g * 16 * 288 + i];
        __syncthreads();
        if (tid < 784) {                       // 16 oc x 49 positions
            int ocs = tid / 49, pos = tid % 49;
            int oh = pos / 7, ow = pos % 7;
            int oc = g * 16 + ocs;
            float a0 = 0.0f, a1 = 0.0f, a2 = 0.0f;
#pragma unroll
            for (int ic = 0; ic < 32; ic++) {
                const float* wp = &sm.c.w3[ocs * 288 + ic * 9];
                const float* sp = &s2p[ic][oh][ow];
                a0 = fmaf(sp[0],  wp[0], fmaf(sp[1],  wp[1], fmaf(sp[2],  wp[2], a0)));
                a1 = fmaf(sp[9],  wp[3], fmaf(sp[10], wp[4], fmaf(sp[11], wp[5], a1)));
                a2 = fmaf(sp[18], wp[6], fmaf(sp[19], wp[7], fmaf(sp[20], wp[8], a2)));
            }
            float sc = bn3_g[oc] * rsqrtf(bn3_v[oc] + 1e-5f);
            float shf = bn3_b[oc] - bn3_m[oc] * sc;
            sm.c.co3[ocs][pos] = fmaxf((a0 + a1 + a2 + conv3_b[oc]) * sc + shf, 0.0f);
        }
        __syncthreads();
        if (tid < 144) {                       // 16 oc x 9 pooled outputs
            int ocs = tid / 9, pp = tid % 9;
            int oh = pp / 3, ow = pp % 3;
            const float* c0 = &sm.c.co3[ocs][(2 * oh) * 7 + 2 * ow];
            s3[(g * 16 + ocs) * 9 + pp] =
                fmaxf(fmaxf(c0[0], c0[1]), fmaxf(c0[7], c0[8]));
        }
        __syncthreads();                       // w3/co3 reused next pass
    }

    // ---- fc1 + relu + fc2 -------------------------------------------------
    const int wid = tid >> 6, lane = tid & 63;
    for (int o = wid; o < 128; o += 16) {      // 16 waves x 8 outputs
        const float* w = fc1_w + o * 576;
        float acc = 0.0f;
#pragma unroll
        for (int jj = 0; jj < 9; jj++)         // lanes across 576: coalesced
            acc = fmaf(s3[jj * 64 + lane], w[jj * 64 + lane], acc);
#pragma unroll
        for (int off = 32; off; off >>= 1) acc += __shfl_down(acc, off);
        if (lane == 0) sm.d.h[o] = fmaxf(acc + fc1_b[o], 0.0f);
    }
    __syncthreads();

    if (wid < 10) {
        const float* w = fc2_w + wid * 128;
        float acc = fmaf(sm.d.h[lane], w[lane], 0.0f);
        acc = fmaf(sm.d.h[64 + lane], w[64 + lane], acc);
#pragma unroll
        for (int off = 32; off; off >>= 1) acc += __shfl_down(acc, off);
        if (lane == 0) out[b * 10 + wid] = acc + fc2_b[wid];
    }
}

extern "C" void kernel_launch(void* const* d_in, const int* in_sizes, int n_in,
                              void* d_out, int out_size, void* d_ws, size_t ws_size,
                              hipStream_t stream) {
    const int*   ct0    = (const int*)d_in[0];
    const int*   cts    = (const int*)d_in[1];
    const int*   y      = (const int*)d_in[2];
    const int*   sk_y   = (const int*)d_in[3];
    const float* bias1  = (const float*)d_in[4];
    const float* bn1_g  = (const float*)d_in[5];
    const float* bn1_b  = (const float*)d_in[6];
    const float* bn1_m  = (const float*)d_in[7];
    const float* bn1_v  = (const float*)d_in[8];
    const float* conv2_w = (const float*)d_in[9];
    const float* conv2_b = (const float*)d_in[10];
    const float* bn2_g  = (const float*)d_in[11];
    const float* bn2_b  = (const float*)d_in[12];
    const float* bn2_m  = (const float*)d_in[13];
    const float* bn2_v  = (const float*)d_in[14];
    const float* conv3_w = (const float*)d_in[15];
    const float* conv3_b = (const float*)d_in[16];
    const float* bn3_g  = (const float*)d_in[17];
    const float* bn3_b  = (const float*)d_in[18];
    const float* bn3_m  = (const float*)d_in[19];
    const float* bn3_v  = (const float*)d_in[20];
    const float* fc1_w  = (const float*)d_in[21];
    const float* fc1_b  = (const float*)d_in[22];
    const float* fc2_w  = (const float*)d_in[23];
    const float* fc2_b  = (const float*)d_in[24];
    const int*   g_in   = (const int*)d_in[25];
    float* out = (float*)d_out;

    char* ws = (char*)d_ws;
    int16_t* table  = (int16_t*)ws;
    float*   pooled = (float*)(ws + POOL_OFF);

    build_table<<<(TBLN + 255) / 256, 256, 0, stream>>>(g_in, table);

    decrypt_pool<<<128, 448, 0, stream>>>(
        ct0, cts, y, sk_y, bias1, bn1_g, bn1_b, bn1_m, bn1_v, table, pooled);

    convnet<<<BATCH, 1024, 0, stream>>>(
        pooled, conv2_w, conv2_b, bn2_g, bn2_b, bn2_m, bn2_v,
        conv3_w, conv3_b, bn3_g, bn3_b, bn3_m, bn3_v,
        fc1_w, fc1_b, fc2_w, fc2_b, out);
}

// Round 8
// 212.798 us; speedup vs baseline: 1.0427x; 1.0427x over previous
//
#include <hip/hip_runtime.h>
#include <stdint.h>

#define PRIME 1000003u
#define NORD  1000002u
#define KCH   16
#define BATCH 4
#define NPATCH 784
#define LLEN  9
#define IPMAX 9000          // |<x,y>| <= 20*50*9
#define TBLN  (2*IPMAX+1)

// Workspace layout (bytes); ws is 256 MiB, we use ~2.1 MB.
//   [0,       2000006)  int16 dlog table
//   [2000128, 2050304)  float pooled [4][16][14][14]
//   [2050304, 2052352)  float hg [4][128]
#define POOL_OFF 2000128
#define HG_OFF   2050304

// Barrett: M = floor(2^41/p) = 2199016; exact for t < 2^40 with one cond-sub.
__device__ __forceinline__ uint32_t mmul(uint32_t a, uint32_t b) {
    uint64_t t = (uint64_t)a * (uint64_t)b;
    uint32_t q = (uint32_t)((t * 2199016ull) >> 41);
    uint32_t r = (uint32_t)t - q * PRIME;
    return (r >= PRIME) ? r - PRIME : r;
}

__device__ __forceinline__ uint32_t mpow(uint32_t base, uint32_t exp) {
    uint32_t r = 1u, b = base;
    while (exp) {
        if (exp & 1u) r = mmul(r, b);
        b = mmul(b, b);
        exp >>= 1;
    }
    return r;
}

// ---------------- Kernel 1: dlog lookup table (int16) -----------------------
__global__ void build_table(const int* __restrict__ g_in, int16_t* __restrict__ table) {
    int e = blockIdx.x * blockDim.x + threadIdx.x;
    if (e >= TBLN) return;
    int es = e - IPMAX;
    uint32_t exp = (es >= 0) ? (uint32_t)es : (uint32_t)(es + (int)NORD);
    table[mpow((uint32_t)g_in[0], exp)] = (int16_t)es;
}

// ---------------- Kernel 2: decrypt + bn1 + relu + pool(28->14) -------------
// 128 blocks x 448; block=(k,b,half). Validated r7: ~2.7us, absmax 0.
__global__ void __launch_bounds__(448) decrypt_pool(
    const int* __restrict__ ct0, const int* __restrict__ cts,
    const int* __restrict__ y, const int* __restrict__ sk_y,
    const float* __restrict__ bias1,
    const float* __restrict__ bn1_g, const float* __restrict__ bn1_b,
    const float* __restrict__ bn1_m, const float* __restrict__ bn1_v,
    const int16_t* __restrict__ table, float* __restrict__ pooled) {
    __shared__ float raw[392];                 // 14 rows x 28 cols
    const int bid = blockIdx.x, tid = threadIdx.x;
    const int pair = bid >> 1, half = bid & 1;
    const int k = pair & 15, b = pair >> 4;

    const int* yrow = y + k * LLEN;
    int yv[LLEN];
#pragma unroll
    for (int i = 0; i < LLEN; i++) yv[i] = yrow[i];          // scalar loads
    const uint32_t sk = (uint32_t)sk_y[k];
    const float sc  = bn1_g[k] * rsqrtf(bn1_v[k] + 1e-5f);
    const float shf = (bias1[k] - bn1_m[k]) * sc + bn1_b[k];

    if (tid < 392) {
        const int j = half * 392 + tid;
        const int* crow = cts + ((b * NPATCH) + j) * LLEN;
        uint32_t c[LLEN];
#pragma unroll
        for (int i = 0; i < LLEN; i++) c[i] = (uint32_t)crow[i];

        uint32_t accp = 1u, accn = 1u;
#pragma unroll
        for (int bit = 5; bit >= 0; bit--) {
            accp = mmul(accp, accp);
            accn = mmul(accn, accn);
#pragma unroll
            for (int i = 0; i < LLEN; i++) {
                int yi = yv[i];
                int ay = (yi > 0) ? yi : -yi;
                if ((ay >> bit) & 1) {
                    if (yi > 0) accp = mmul(accp, c[i]);
                    else        accn = mmul(accn, c[i]);
                }
            }
        }

        uint32_t den = mmul(mpow((uint32_t)ct0[b * NPATCH + j], sk), accn);
        uint32_t val = mmul(accp, mpow(den, PRIME - 2u));    // const exp: unrolls

        int ip = (int)table[val];              // guaranteed hit, |ip|<=9000
        raw[tid] = fmaxf(fmaf((float)ip, sc * 1e-4f, shf), 0.0f);
    }
    __syncthreads();
    if (tid < 98) {                            // pool 14x28 -> 7x14
        int pyl = tid / 14, px = tid % 14;
        const float* r0 = &raw[(2 * pyl) * 28 + 2 * px];
        float m = fmaxf(fmaxf(r0[0], r0[1]), fmaxf(r0[28], r0[29]));
        pooled[((b * KCH) + k) * 196 + (half * 7 + pyl) * 14 + px] = m;
    }
}

// ---------------- Kernel 3: conv2 + conv3 + fc1 slice, 64 blocks ------------
// block = (b, og): full conv2+conv3 REPLICATED per block (parallel CUs make
// replication free; 8 blocks/XCD share weight lines via L2 — fixes r7's
// 4-CU latency serialization), then fc1 outputs [og*8, og*8+8) only
// (18.4 KB weight slice/block vs 294 KB). w3 slices and the fc1 slice are
// reg-staged ahead of use (issue during previous pass, ds_write after its
// barrier) so no pass stalls on a cold fetch.
__global__ void __launch_bounds__(1024) bigconv(
    const float* __restrict__ pooled,
    const float* __restrict__ conv2_w, const float* __restrict__ conv2_b,
    const float* __restrict__ bn2_g, const float* __restrict__ bn2_b,
    const float* __restrict__ bn2_m, const float* __restrict__ bn2_v,
    const float* __restrict__ conv3_w, const float* __restrict__ conv3_b,
    const float* __restrict__ bn3_g, const float* __restrict__ bn3_b,
    const float* __restrict__ bn3_m, const float* __restrict__ bn3_v,
    const float* __restrict__ fc1_w, const float* __restrict__ fc1_b,
    float* __restrict__ hg) {
    const int b = blockIdx.x >> 4, og = blockIdx.x & 15;
    const int tid = threadIdx.x;

    __shared__ float s2p[32][9][9];            // 10.4 KB, conv2 -> conv3
    __shared__ float s3[576];                  // 2.3 KB,  conv3 -> fc1
    __shared__ float w3buf[2][16 * 288];       // 36.9 KB, double-buffered
    __shared__ float co3[16][49];              // 3.1 KB
    __shared__ union {
        struct { float s1p[16][16][16]; float w2[32 * 144]; float co[4][196]; } a; // 38 KB (conv2 only)
        float fc1w[8 * 576];                                                       // 18.4 KB (fc1)
    } u;                                       // total ~90.6 KB

    // ---- initial stage: all loads issued together for max MLP -------------
    for (int i = tid; i < 4096; i += 1024) ((float*)u.a.s1p)[i] = 0.0f;
    for (int i = tid; i < 2592; i += 1024) ((float*)s2p)[i] = 0.0f;
    float4 pw3a, pw3b;                         // w3 slice-1 prefetch regs
    {
        const float4* s2w = (const float4*)conv2_w;   // 1152 float4
        float4* d2 = (float4*)u.a.w2;
        d2[tid] = s2w[tid];
        if (tid < 128) d2[1024 + tid] = s2w[1024 + tid];
        const float4* s30 = (const float4*)conv3_w;   // slice 0 -> buf0
        float4* d3 = (float4*)w3buf[0];
        d3[tid] = s30[tid];
        if (tid < 128) d3[1024 + tid] = s30[1024 + tid];
        const float4* s31 = (const float4*)conv3_w + 1152;  // slice 1 -> regs
        pw3a = s31[tid];
        if (tid < 128) pw3b = s31[1024 + tid];
    }
    __syncthreads();
    for (int i = tid; i < 16 * 196; i += 1024) {
        int ic = i / 196, pos = i % 196;
        u.a.s1p[ic][pos / 14 + 1][pos % 14 + 1] = pooled[(b * KCH + ic) * 196 + pos];
    }
    __syncthreads();

    // ---- conv2 + bn2 + relu + pool(14->7): 8 passes x 4 oc ----------------
    for (int g = 0; g < 8; ++g) {
        if (tid < 784) {
            int ocs = tid / 196, pos = tid % 196;
            int oh = pos / 14, ow = pos % 14;
            int oc = g * 4 + ocs;
            float a0 = 0.0f, a1 = 0.0f, a2 = 0.0f;
#pragma unroll
            for (int ic = 0; ic < 16; ic++) {
                const float* wp = &u.a.w2[oc * 144 + ic * 9];
                const float* sp = &u.a.s1p[ic][oh][ow];
                a0 = fmaf(sp[0],  wp[0], fmaf(sp[1],  wp[1], fmaf(sp[2],  wp[2], a0)));
                a1 = fmaf(sp[16], wp[3], fmaf(sp[17], wp[4], fmaf(sp[18], wp[5], a1)));
                a2 = fmaf(sp[32], wp[6], fmaf(sp[33], wp[7], fmaf(sp[34], wp[8], a2)));
            }
            float sc = bn2_g[oc] * rsqrtf(bn2_v[oc] + 1e-5f);
            float shf = bn2_b[oc] - bn2_m[oc] * sc;
            u.a.co[ocs][pos] = fmaxf((a0 + a1 + a2 + conv2_b[oc]) * sc + shf, 0.0f);
        }
        __syncthreads();
        if (tid < 196) {
            int ocs = tid / 49, pp = tid % 49;
            int oh = pp / 7, ow = pp % 7;
            const float* c0 = &u.a.co[ocs][(2 * oh) * 14 + 2 * ow];
            s2p[g * 4 + ocs][oh + 1][ow + 1] =
                fmaxf(fmaxf(c0[0], c0[1]), fmaxf(c0[14], c0[15]));
        }
        __syncthreads();                       // co reused next pass
    }
    // union-a dead from here (conv2 done). Land slice1; issue slice2 + fc1.
    float4 pfca, pfcb;
    {
        float4* d = (float4*)w3buf[1];
        d[tid] = pw3a;
        if (tid < 128) d[1024 + tid] = pw3b;
        const float4* s32 = (const float4*)conv3_w + 2 * 1152;
        pw3a = s32[tid];
        if (tid < 128) pw3b = s32[1024 + tid];
        const float4* sf = (const float4*)(fc1_w + og * 4608);  // 8 outputs x 576
        pfca = sf[tid];
        if (tid < 128) pfcb = sf[1024 + tid];
    }

    // ---- conv3 + bn3 + relu + pool(7->3): 4 passes x 16 oc ----------------
    for (int g = 0; g < 4; ++g) {
        if (tid < 784) {
            int ocs = tid / 49, pos = tid % 49;
            int oh = pos / 7, ow = pos % 7;
            int oc = g * 16 + ocs;
            const float* w3p = w3buf[g & 1];
            float a0 = 0.0f, a1 = 0.0f, a2 = 0.0f;
#pragma unroll
            for (int ic = 0; ic < 32; ic++) {
                const float* wp = &w3p[ocs * 288 + ic * 9];
                const float* sp = &s2p[ic][oh][ow];
                a0 = fmaf(sp[0],  wp[0], fmaf(sp[1],  wp[1], fmaf(sp[2],  wp[2], a0)));
                a1 = fmaf(sp[9],  wp[3], fmaf(sp[10], wp[4], fmaf(sp[11], wp[5], a1)));
                a2 = fmaf(sp[18], wp[6], fmaf(sp[19], wp[7], fmaf(sp[20], wp[8], a2)));
            }
            float sc = bn3_g[oc] * rsqrtf(bn3_v[oc] + 1e-5f);
            float shf = bn3_b[oc] - bn3_m[oc] * sc;
            co3[ocs][pos] = fmaxf((a0 + a1 + a2 + conv3_b[oc]) * sc + shf, 0.0f);
        }
        __syncthreads();                       // w3buf[g&1] reads done
        if (tid < 144) {
            int ocs = tid / 9, pp = tid % 9;
            int oh = pp / 3, ow = pp % 3;
            const float* c0 = &co3[ocs][(2 * oh) * 7 + 2 * ow];
            s3[(g * 16 + ocs) * 9 + pp] =
                fmaxf(fmaxf(c0[0], c0[1]), fmaxf(c0[7], c0[8]));
        }
        if (g == 0) {                          // slice2 -> buf0 (free), issue slice3
            float4* d = (float4*)w3buf[0];
            d[tid] = pw3a;
            if (tid < 128) d[1024 + tid] = pw3b;
            const float4* s33 = (const float4*)conv3_w + 3 * 1152;
            pw3a = s33[tid];
            if (tid < 128) pw3b = s33[1024 + tid];
        } else if (g == 1) {                   // slice3 -> buf1; fc1 slice -> LDS
            float4* d = (float4*)w3buf[1];
            d[tid] = pw3a;
            if (tid < 128) d[1024 + tid] = pw3b;
            float4* df = (float4*)u.fc1w;
            df[tid] = pfca;
            if (tid < 128) df[1024 + tid] = pfcb;
        }
        __syncthreads();
    }

    // ---- fc1 + relu for outputs og*8 .. og*8+7 ----------------------------
    const int wid = tid >> 6, lane = tid & 63;
    if (wid < 8) {
        int o = og * 8 + wid;
        const float* w = u.fc1w + wid * 576;
        float acc = 0.0f;
#pragma unroll
        for (int jj = 0; jj < 9; jj++)
            acc = fmaf(s3[jj * 64 + lane], w[jj * 64 + lane], acc);
#pragma unroll
        for (int off = 32; off; off >>= 1) acc += __shfl_down(acc, off);
        if (lane == 0) hg[b * 128 + o] = fmaxf(acc + fc1_b[o], 0.0f);
    }
}

// ---------------- Kernel 4: fc2 ---------------------------------------------
__global__ void __launch_bounds__(640) fc2k(
    const float* __restrict__ hg,
    const float* __restrict__ fc2_w, const float* __restrict__ fc2_b,
    float* __restrict__ out) {
    const int b = blockIdx.x, tid = threadIdx.x;
    __shared__ float h[128];
    if (tid < 128) h[tid] = hg[b * 128 + tid];
    __syncthreads();
    const int wid = tid >> 6, lane = tid & 63;
    if (wid < 10) {
        const float* w = fc2_w + wid * 128;
        float acc = fmaf(h[lane], w[lane], 0.0f);
        acc = fmaf(h[64 + lane], w[64 + lane], acc);
#pragma unroll
        for (int off = 32; off; off >>= 1) acc += __shfl_down(acc, off);
        if (lane == 0) out[b * 10 + wid] = acc + fc2_b[wid];
    }
}

extern "C" void kernel_launch(void* const* d_in, const int* in_sizes, int n_in,
                              void* d_out, int out_size, void* d_ws, size_t ws_size,
                              hipStream_t stream) {
    const int*   ct0    = (const int*)d_in[0];
    const int*   cts    = (const int*)d_in[1];
    const int*   y      = (const int*)d_in[2];
    const int*   sk_y   = (const int*)d_in[3];
    const float* bias1  = (const float*)d_in[4];
    const float* bn1_g  = (const float*)d_in[5];
    const float* bn1_b  = (const float*)d_in[6];
    const float* bn1_m  = (const float*)d_in[7];
    const float* bn1_v  = (const float*)d_in[8];
    const float* conv2_w = (const float*)d_in[9];
    const float* conv2_b = (const float*)d_in[10];
    const float* bn2_g  = (const float*)d_in[11];
    const float* bn2_b  = (const float*)d_in[12];
    const float* bn2_m  = (const float*)d_in[13];
    const float* bn2_v  = (const float*)d_in[14];
    const float* conv3_w = (const float*)d_in[15];
    const float* conv3_b = (const float*)d_in[16];
    const float* bn3_g  = (const float*)d_in[17];
    const float* bn3_b  = (const float*)d_in[18];
    const float* bn3_m  = (const float*)d_in[19];
    const float* bn3_v  = (const float*)d_in[20];
    const float* fc1_w  = (const float*)d_in[21];
    const float* fc1_b  = (const float*)d_in[22];
    const float* fc2_w  = (const float*)d_in[23];
    const float* fc2_b  = (const float*)d_in[24];
    const int*   g_in   = (const int*)d_in[25];
    float* out = (float*)d_out;

    char* ws = (char*)d_ws;
    int16_t* table  = (int16_t*)ws;
    float*   pooled = (float*)(ws + POOL_OFF);
    float*   hg     = (float*)(ws + HG_OFF);

    build_table<<<(TBLN + 255) / 256, 256, 0, stream>>>(g_in, table);

    decrypt_pool<<<128, 448, 0, stream>>>(
        ct0, cts, y, sk_y, bias1, bn1_g, bn1_b, bn1_m, bn1_v, table, pooled);

    bigconv<<<BATCH * 16, 1024, 0, stream>>>(
        pooled, conv2_w, conv2_b, bn2_g, bn2_b, bn2_m, bn2_v,
        conv3_w, conv3_b, bn3_g, bn3_b, bn3_m, bn3_v, fc1_w, fc1_b, hg);

    fc2k<<<BATCH, 640, 0, stream>>>(hg, fc2_w, fc2_b, out);
}

// Round 9
// 135.443 us; speedup vs baseline: 1.6383x; 1.5711x over previous
//
#include <hip/hip_runtime.h>
#include <stdint.h>

#define PRIME 1000003u
#define NORD  1000002u
#define KCH   16
#define BATCH 4
#define NPATCH 784
#define LLEN  9
#define IPMAX 9000          // |<x,y>| <= 20*50*9
#define TBLN  (2*IPMAX+1)
#define NBLK  128           // fused grid (all co-resident; 128 < 256 CUs)
#define TPB   832           // 13 waves

// Workspace offsets (bytes); ws is 256 MiB, we use ~2.1 MB.
#define CTR_OFF   2000064   // 32 counters, 64 B apart (2048 B)
#define POOL_OFF  2008256   // float pooled [4][16][14][14]  (50176 B)
#define S2G_OFF   2058432   // float s2g    [4][32][7][7]    (25088 B)
#define S3G_OFF   2083520   // float s3g    [4][576]         (9216 B)
#define HG_OFF    2092736   // float hg     [4][128]         (2048 B)

// Barrett: M = floor(2^41/p) = 2199016; exact for t < 2^40 with one cond-sub.
__device__ __forceinline__ uint32_t mmul(uint32_t a, uint32_t b) {
    uint64_t t = (uint64_t)a * (uint64_t)b;
    uint32_t q = (uint32_t)((t * 2199016ull) >> 41);
    uint32_t r = (uint32_t)t - q * PRIME;
    return (r >= PRIME) ? r - PRIME : r;
}

__device__ __forceinline__ uint32_t mpow(uint32_t base, uint32_t exp) {
    uint32_t r = 1u, b = base;
    while (exp) {
        if (exp & 1u) r = mmul(r, b);
        b = mmul(b, b);
        exp >>= 1;
    }
    return r;
}

// ---- Fence-free cross-phase data access (validated r2-r6: absmax 0) --------
__device__ __forceinline__ void cstore(float* p, float v) {
    __hip_atomic_store(p, v, __ATOMIC_RELAXED, __HIP_MEMORY_SCOPE_AGENT);
}
__device__ __forceinline__ float cload(const float* p) {
    return __hip_atomic_load(p, __ATOMIC_RELAXED, __HIP_MEMORY_SCOPE_AGENT);
}

// ---- Grid barrier: 32-way split arrival counters (r3 mechanism, widened) ---
// r3 measured ~4.5us/barrier at 8 lines (<=16 serialized RMWs/line). 32 lines
// cap it at 4 RMWs/line (~0.4us). Waiter: one thread, 32 UNROLLED independent
// loads (all in flight -> one miss latency per poll round), sum, compare.
// (r5 lesson: never poll serially; r6 lesson: this sum-poll is the fast one.)
__device__ __forceinline__ void arrive32(unsigned* ctrs, int bid) {
    __syncthreads();   // all block stores vmcnt-retired before the add
    if (threadIdx.x == 0)
        __hip_atomic_fetch_add(&ctrs[(bid & 31) * 16], 1u,
                               __ATOMIC_RELAXED, __HIP_MEMORY_SCOPE_AGENT);
}
__device__ __forceinline__ void wait32(unsigned* ctrs, unsigned target) {
    if (threadIdx.x == 0) {
        for (;;) {
            unsigned s = 0;
#pragma unroll
            for (int i = 0; i < 32; i++)
                s += __hip_atomic_load(&ctrs[i * 16],
                                       __ATOMIC_RELAXED, __HIP_MEMORY_SCOPE_AGENT);
            if (s >= target) break;
            __builtin_amdgcn_s_sleep(8);
        }
    }
    __syncthreads();
}

// ---------------- Kernel 1: dlog lookup table (int16) -----------------------
// table[g^e mod p] = e for e in [-9000,9000]. Also zeroes the 32 counters
// (ws re-poisoned between iterations; kernel boundary orders the zeroing).
__global__ void build_table(const int* __restrict__ g_in, int16_t* __restrict__ table,
                            unsigned* __restrict__ ctrs) {
    int e = blockIdx.x * blockDim.x + threadIdx.x;
    if (e >= TBLN) return;
    if (e < 32)
        __hip_atomic_store(&ctrs[e * 16], 0u, __ATOMIC_RELAXED, __HIP_MEMORY_SCOPE_AGENT);
    int es = e - IPMAX;
    uint32_t exp = (es >= 0) ? (uint32_t)es : (uint32_t)(es + (int)NORD);
    table[mpow((uint32_t)g_in[0], exp)] = (int16_t)es;
}

// ---------------- Kernel 2: fused pipeline ----------------------------------
// 128 blocks x 832. Phases (cumulative arrival targets):
//   A : decrypt+bn1+relu+pool, (k,b,half)     all 128   -> 128
//   B : conv2+bn2+relu+pool, 4 oc/block       bid<32    -> 160
//   C : conv3+bn3+relu+pool, 4 oc/block       bid<64    -> 224
//   D1: fc1+relu, 8 outputs/block             bid<64    -> 288
//   D2: fc2                                   bid<4
// All input-independent LDS prep (weight loads, halo zeroing) is issued
// BEFORE the wait (overlaps the producer's tail); per-block conv work stays
// sliced (4 oc) — r7/r8 showed the conv stack is LDS-instruction-throughput
// bound (~60us/CU if one block does it all).
__global__ void __launch_bounds__(TPB) fused(
    const int* __restrict__ ct0, const int* __restrict__ cts,
    const int* __restrict__ y, const int* __restrict__ sk_y,
    const float* __restrict__ bias1,
    const float* __restrict__ bn1_g, const float* __restrict__ bn1_b,
    const float* __restrict__ bn1_m, const float* __restrict__ bn1_v,
    const float* __restrict__ conv2_w, const float* __restrict__ conv2_b,
    const float* __restrict__ bn2_g, const float* __restrict__ bn2_b,
    const float* __restrict__ bn2_m, const float* __restrict__ bn2_v,
    const float* __restrict__ conv3_w, const float* __restrict__ conv3_b,
    const float* __restrict__ bn3_g, const float* __restrict__ bn3_b,
    const float* __restrict__ bn3_m, const float* __restrict__ bn3_v,
    const float* __restrict__ fc1_w, const float* __restrict__ fc1_b,
    const float* __restrict__ fc2_w, const float* __restrict__ fc2_b,
    const int16_t* __restrict__ table,
    float* __restrict__ pooled, float* __restrict__ s2g, float* __restrict__ s3g,
    float* __restrict__ hg, float* __restrict__ out, unsigned* __restrict__ ctrs) {

    __shared__ union {
        float raw[392];                                                          // A: 1.6 KB
        struct { float s1p[16][16][16]; float w[4][144]; float co[4][196]; } c2; // 21.4 KB
        struct { float s2p[32][9][9];  float w[4][288]; float co[4][49]; } c3;   // 15.4 KB
        struct { float s3[576]; float w[8 * 576]; } d1;                          // 20.7 KB
        struct { float h[128]; float w[10 * 128]; } d2;                          // 5.5 KB
    } sm;

    const int bid = blockIdx.x;
    const int tid = threadIdx.x;

    // ---------------- Phase A: decrypt + bn1 + relu + pool(28->14) ---------
    // block = (k, b, half): half = 14 raw rows = 392 patches. (r6/r7 code.)
    {
        const int pair = bid >> 1, half = bid & 1;
        const int k = pair & 15, b = pair >> 4;
        const int* yrow = y + k * LLEN;
        int yv[LLEN];
#pragma unroll
        for (int i = 0; i < LLEN; i++) yv[i] = yrow[i];      // scalar loads
        const uint32_t sk = (uint32_t)sk_y[k];
        const float sc  = bn1_g[k] * rsqrtf(bn1_v[k] + 1e-5f);
        const float shf = (bias1[k] - bn1_m[k]) * sc + bn1_b[k];

        if (tid < 392) {
            const int j = half * 392 + tid;
            const int* crow = cts + ((b * NPATCH) + j) * LLEN;
            uint32_t c[LLEN];
#pragma unroll
            for (int i = 0; i < LLEN; i++) c[i] = (uint32_t)crow[i];

            // Shamir: |y_i| <= 50 < 64 (6 bits). Branch conds block-uniform.
            uint32_t accp = 1u, accn = 1u;
#pragma unroll
            for (int bit = 5; bit >= 0; bit--) {
                accp = mmul(accp, accp);
                accn = mmul(accn, accn);
#pragma unroll
                for (int i = 0; i < LLEN; i++) {
                    int yi = yv[i];
                    int ay = (yi > 0) ? yi : -yi;
                    if ((ay >> bit) & 1) {
                        if (yi > 0) accp = mmul(accp, c[i]);
                        else        accn = mmul(accn, c[i]);
                    }
                }
            }

            uint32_t den = mmul(mpow((uint32_t)ct0[b * NPATCH + j], sk), accn);
            uint32_t val = mmul(accp, mpow(den, PRIME - 2u));  // const exp: unrolls

            int ip = (int)table[val];              // guaranteed hit, |ip|<=9000
            sm.raw[tid] = fmaxf(fmaf((float)ip, sc * 1e-4f, shf), 0.0f);
        }
        __syncthreads();
        if (tid < 98) {                            // pool 14x28 -> 7x14
            int pyl = tid / 14, px = tid % 14;
            const float* r0 = &sm.raw[(2 * pyl) * 28 + 2 * px];
            float m = fmaxf(fmaxf(r0[0], r0[1]), fmaxf(r0[28], r0[29]));
            cstore(&pooled[((b * KCH) + k) * 196 + (half * 7 + pyl) * 14 + px], m);
        }
    }
    arrive32(ctrs, bid);                           // -> 128
    if (bid >= 64) return;

    // ---------------- Phase B: conv2 + bn2 + relu + pool(14->7), 4 oc ------
    if (bid < 32) {
        const int b = bid >> 3, base_oc = (bid & 7) * 4;

        // prep (input-independent) BEFORE the wait
        for (int i = tid; i < 16 * 16 * 16; i += TPB)
            ((float*)sm.c2.s1p)[i] = 0.0f;
        if (tid < 576) sm.c2.w[tid / 144][tid % 144] =
            conv2_w[(base_oc + tid / 144) * 144 + tid % 144];

        wait32(ctrs, 128);                         // ends with __syncthreads

        for (int i = tid; i < 16 * 196; i += TPB) {
            int ic = i / 196, pos = i % 196;
            sm.c2.s1p[ic][pos / 14 + 1][pos % 14 + 1] =
                cload(&pooled[((b * KCH) + ic) * 196 + pos]);
        }
        __syncthreads();

        if (tid < 784) {                           // 4 oc x 196 positions
            int ocs = tid / 196, pos = tid % 196;
            int oh = pos / 14, ow = pos % 14;
            int oc = base_oc + ocs;
            float a0 = 0.0f, a1 = 0.0f, a2 = 0.0f;
#pragma unroll
            for (int ic = 0; ic < 16; ic++) {
                const float* wp = &sm.c2.w[ocs][ic * 9];
                const float* sp = &sm.c2.s1p[ic][oh][ow];
                a0 = fmaf(sp[0],  wp[0], fmaf(sp[1],  wp[1], fmaf(sp[2],  wp[2], a0)));
                a1 = fmaf(sp[16], wp[3], fmaf(sp[17], wp[4], fmaf(sp[18], wp[5], a1)));
                a2 = fmaf(sp[32], wp[6], fmaf(sp[33], wp[7], fmaf(sp[34], wp[8], a2)));
            }
            float sc = bn2_g[oc] * rsqrtf(bn2_v[oc] + 1e-5f);
            float shf = bn2_b[oc] - bn2_m[oc] * sc;
            sm.c2.co[ocs][pos] = fmaxf((a0 + a1 + a2 + conv2_b[oc]) * sc + shf, 0.0f);
        }
        __syncthreads();

        if (tid < 196) {                           // 4 oc x 49 pooled outputs
            int ocs = tid / 49, pp = tid % 49;
            int oh = pp / 7, ow = pp % 7;
            const float* c0 = &sm.c2.co[ocs][(2 * oh) * 14 + 2 * ow];
            cstore(&s2g[((b * 32 + base_oc + ocs) * 49) + pp],
                   fmaxf(fmaxf(c0[0], c0[1]), fmaxf(c0[14], c0[15])));
        }
        arrive32(ctrs, bid);                       // -> 160
    }

    // ---------------- Phase C: conv3 + bn3 + relu + pool(7->3), 4 oc -------
    {
        const int b = bid >> 4, ocg = bid & 15;

        // prep BEFORE the wait (preceding arrive's __syncthreads orders the
        // LDS-union reuse for bid<32; bid 32-63 come straight from A-arrive)
        for (int i = tid; i < 32 * 81; i += TPB)
            ((float*)sm.c3.s2p)[i] = 0.0f;
        for (int i = tid; i < 4 * 288; i += TPB) {
            int w2 = i / 288, rr = i % 288;
            sm.c3.w[w2][rr] = conv3_w[(ocg * 4 + w2) * 288 + rr];
        }

        wait32(ctrs, 160);                         // ends with __syncthreads

        for (int i = tid; i < 32 * 49; i += TPB) {
            int ic = i / 49, pos = i % 49;
            sm.c3.s2p[ic][pos / 7 + 1][pos % 7 + 1] =
                cload(&s2g[((b * 32 + ic) * 49) + pos]);
        }
        __syncthreads();

        const int wid = tid >> 6, lane = tid & 63;
        if (wid < 4 && lane < 49) {
            int oh = lane / 7, ow = lane % 7;
            float a0 = 0.0f, a1 = 0.0f, a2 = 0.0f;
#pragma unroll
            for (int ic = 0; ic < 32; ic++) {
                const float* wp = &sm.c3.w[wid][ic * 9];
                const float* sp = &sm.c3.s2p[ic][oh][ow];
                a0 = fmaf(sp[0],  wp[0], fmaf(sp[1],  wp[1], fmaf(sp[2],  wp[2], a0)));
                a1 = fmaf(sp[9],  wp[3], fmaf(sp[10], wp[4], fmaf(sp[11], wp[5], a1)));
                a2 = fmaf(sp[18], wp[6], fmaf(sp[19], wp[7], fmaf(sp[20], wp[8], a2)));
            }
            int oc = ocg * 4 + wid;
            float sc = bn3_g[oc] * rsqrtf(bn3_v[oc] + 1e-5f);
            float shf = bn3_b[oc] - bn3_m[oc] * sc;
            sm.c3.co[wid][lane] = fmaxf((a0 + a1 + a2 + conv3_b[oc]) * sc + shf, 0.0f);
        }
        __syncthreads();

        if (tid < 36) {
            int w2 = tid / 9, p = tid % 9;
            int oh = p / 3, ow = p % 3;
            const float* c0 = &sm.c3.co[w2][(2 * oh) * 7 + 2 * ow];
            cstore(&s3g[b * 576 + (ocg * 4 + w2) * 9 + p],
                   fmaxf(fmaxf(c0[0], c0[1]), fmaxf(c0[7], c0[8])));
        }
        arrive32(ctrs, bid);                       // -> 224
    }

    // ---------------- Phase D1: fc1 + relu (8 outputs / block) -------------
    {
        const int b = bid >> 4, og = bid & 15;

        // prefetch this block's 18.4 KB fc1 slice BEFORE the wait (fixes
        // r6's 294KB-per-CU mistake: slice is split across 64 blocks AND
        // its load overlaps phase C's tail)
        for (int i = tid; i < 8 * 576; i += TPB)
            sm.d1.w[i] = fc1_w[og * 8 * 576 + i];

        wait32(ctrs, 224);                         // ends with __syncthreads

        if (tid < 576) sm.d1.s3[tid] = cload(&s3g[b * 576 + tid]);
        __syncthreads();

        const int wid = tid >> 6, lane = tid & 63;
        if (wid < 8) {
            int o = og * 8 + wid;
            const float* w = sm.d1.w + wid * 576;
            float acc = 0.0f;
#pragma unroll
            for (int jj = 0; jj < 9; jj++)         // lanes across 576: coalesced
                acc = fmaf(sm.d1.s3[jj * 64 + lane], w[jj * 64 + lane], acc);
#pragma unroll
            for (int off = 32; off; off >>= 1) acc += __shfl_down(acc, off);
            if (lane == 0) cstore(&hg[b * 128 + o], fmaxf(acc + fc1_b[o], 0.0f));
        }
        arrive32(ctrs, bid);                       // -> 288
    }
    if (bid >= BATCH) return;

    // ---------------- Phase D2: fc2 (4 blocks) -----------------------------
    {
        const int b = bid;
        for (int i = tid; i < 10 * 128; i += TPB) sm.d2.w[i] = fc2_w[i];  // pre-wait

        wait32(ctrs, 288);

        if (tid < 128) sm.d2.h[tid] = cload(&hg[b * 128 + tid]);
        __syncthreads();

        const int wid = tid >> 6, lane = tid & 63;
        if (wid < 10) {
            const float* w = sm.d2.w + wid * 128;
            float acc = fmaf(sm.d2.h[lane], w[lane], 0.0f);
            acc = fmaf(sm.d2.h[64 + lane], w[64 + lane], acc);
#pragma unroll
            for (int off = 32; off; off >>= 1) acc += __shfl_down(acc, off);
            if (lane == 0) out[b * 10 + wid] = acc + fc2_b[wid];
        }
    }
}

extern "C" void kernel_launch(void* const* d_in, const int* in_sizes, int n_in,
                              void* d_out, int out_size, void* d_ws, size_t ws_size,
                              hipStream_t stream) {
    const int*   ct0    = (const int*)d_in[0];
    const int*   cts    = (const int*)d_in[1];
    const int*   y      = (const int*)d_in[2];
    const int*   sk_y   = (const int*)d_in[3];
    const float* bias1  = (const float*)d_in[4];
    const float* bn1_g  = (const float*)d_in[5];
    const float* bn1_b  = (const float*)d_in[6];
    const float* bn1_m  = (const float*)d_in[7];
    const float* bn1_v  = (const float*)d_in[8];
    const float* conv2_w = (const float*)d_in[9];
    const float* conv2_b = (const float*)d_in[10];
    const float* bn2_g  = (const float*)d_in[11];
    const float* bn2_b  = (const float*)d_in[12];
    const float* bn2_m  = (const float*)d_in[13];
    const float* bn2_v  = (const float*)d_in[14];
    const float* conv3_w = (const float*)d_in[15];
    const float* conv3_b = (const float*)d_in[16];
    const float* bn3_g  = (const float*)d_in[17];
    const float* bn3_b  = (const float*)d_in[18];
    const float* bn3_m  = (const float*)d_in[19];
    const float* bn3_v  = (const float*)d_in[20];
    const float* fc1_w  = (const float*)d_in[21];
    const float* fc1_b  = (const float*)d_in[22];
    const float* fc2_w  = (const float*)d_in[23];
    const float* fc2_b  = (const float*)d_in[24];
    const int*   g_in   = (const int*)d_in[25];
    float* out = (float*)d_out;

    char* ws = (char*)d_ws;
    int16_t*  table = (int16_t*)ws;
    unsigned* ctrs  = (unsigned*)(ws + CTR_OFF);
    float* pooled = (float*)(ws + POOL_OFF);
    float* s2g    = (float*)(ws + S2G_OFF);
    float* s3g    = (float*)(ws + S3G_OFF);
    float* hg     = (float*)(ws + HG_OFF);

    build_table<<<(TBLN + 255) / 256, 256, 0, stream>>>(g_in, table, ctrs);

    fused<<<NBLK, TPB, 0, stream>>>(
        ct0, cts, y, sk_y, bias1, bn1_g, bn1_b, bn1_m, bn1_v,
        conv2_w, conv2_b, bn2_g, bn2_b, bn2_m, bn2_v,
        conv3_w, conv3_b, bn3_g, bn3_b, bn3_m, bn3_v,
        fc1_w, fc1_b, fc2_w, fc2_b, table, pooled, s2g, s3g, hg, out, ctrs);
}

// Round 10
// 132.444 us; speedup vs baseline: 1.6754x; 1.0226x over previous
//
#include <hip/hip_runtime.h>
#include <stdint.h>

#define PRIME 1000003u
#define NORD  1000002u
#define KCH   16
#define BATCH 4
#define NPATCH 784
#define LLEN  9
#define IPMAX 9000          // |<x,y>| <= 20*50*9
#define TBLN  (2*IPMAX+1)
#define NBLK  128           // fused grid (all co-resident; 128 < 256 CUs)
#define TPB   1024          // 16 waves

// Workspace offsets (bytes); ws is 256 MiB, we use ~2.1 MB.
#define CTR_OFF   2000064   // 32 counters, 64 B apart (2048 B)
#define POOL_OFF  2008256   // float pooled [4][16][14][14]  (50176 B)
#define C3P_OFF   2058432   // float c3pre  [4][64][7][7]    (50176 B) accumulator

// Barrett: M = floor(2^41/p) = 2199016; exact for t < 2^40 with one cond-sub.
__device__ __forceinline__ uint32_t mmul(uint32_t a, uint32_t b) {
    uint64_t t = (uint64_t)a * (uint64_t)b;
    uint32_t q = (uint32_t)((t * 2199016ull) >> 41);
    uint32_t r = (uint32_t)t - q * PRIME;
    return (r >= PRIME) ? r - PRIME : r;
}

__device__ __forceinline__ uint32_t mpow(uint32_t base, uint32_t exp) {
    uint32_t r = 1u, b = base;
    while (exp) {
        if (exp & 1u) r = mmul(r, b);
        b = mmul(b, b);
        exp >>= 1;
    }
    return r;
}

// ---- Fence-free cross-phase data access (validated r2-r9: absmax 0) --------
__device__ __forceinline__ void cstore(float* p, float v) {
    __hip_atomic_store(p, v, __ATOMIC_RELAXED, __HIP_MEMORY_SCOPE_AGENT);
}
__device__ __forceinline__ float cload(const float* p) {
    return __hip_atomic_load(p, __ATOMIC_RELAXED, __HIP_MEMORY_SCOPE_AGENT);
}

// ---- Grid barrier: 32-way split counters (r9 mechanism; floor ~4.5us) ------
__device__ __forceinline__ void arrive32(unsigned* ctrs, int bid) {
    __syncthreads();   // all block stores/atomics vmcnt-retired before the add
    if (threadIdx.x == 0)
        __hip_atomic_fetch_add(&ctrs[(bid & 31) * 16], 1u,
                               __ATOMIC_RELAXED, __HIP_MEMORY_SCOPE_AGENT);
}
__device__ __forceinline__ void wait32(unsigned* ctrs, unsigned target) {
    if (threadIdx.x == 0) {
        for (;;) {
            unsigned s = 0;
#pragma unroll
            for (int i = 0; i < 32; i++)
                s += __hip_atomic_load(&ctrs[i * 16],
                                       __ATOMIC_RELAXED, __HIP_MEMORY_SCOPE_AGENT);
            if (s >= target) break;
            __builtin_amdgcn_s_sleep(4);
        }
    }
    __syncthreads();
}

// ---------------- Kernel 1: dlog table + accumulator zeroing ----------------
// table[g^e mod p] = e for e in [-9000,9000]. Also zeroes: 32 barrier ctrs,
// the conv3 pre-activation accumulator c3pre (12544 f), and out (40 f) —
// all are atomically accumulated into by the fused kernel; ws/out re-poisoned
// between iterations, and the kernel boundary orders the zeroing.
__global__ void build_table(const int* __restrict__ g_in, int16_t* __restrict__ table,
                            unsigned* __restrict__ ctrs, float* __restrict__ c3pre,
                            float* __restrict__ out) {
    int e = blockIdx.x * blockDim.x + threadIdx.x;
    if (e >= TBLN) return;
    if (e < 32)
        __hip_atomic_store(&ctrs[e * 16], 0u, __ATOMIC_RELAXED, __HIP_MEMORY_SCOPE_AGENT);
    if (e < BATCH * 64 * 49) cstore(&c3pre[e], 0.0f);
    if (e < BATCH * 10) cstore(&out[e], 0.0f);
    int es = e - IPMAX;
    uint32_t exp = (es >= 0) ? (uint32_t)es : (uint32_t)(es + (int)NORD);
    table[mpow((uint32_t)g_in[0], exp)] = (int16_t)es;
}

// ---------------- Kernel 2: fused pipeline, TWO grid barriers ---------------
// 128 blocks x 1024. Phases (cumulative arrival targets):
//   A : decrypt+bn1+relu+pool, (k,b,half)            all 128     -> 128
//   B : conv2+bn2+relu+pool (4 oc) + conv3-PARTIAL
//       (4 ic -> all 64 oc) atomicAdd into c3pre     bid<32      -> 160
//   CD: bn3+relu+pool + fc1 (16 outs) + fc2-PARTIAL
//       atomicAdd into out                           bid in [32,64)
// conv3 and fc2 are linear in the sliced inputs -> producers push partial
// sums (atomicAdd) instead of a barrier handoff. Deletes 2 of 4 barriers
// (r9 post-mortem: each handoff costs a ~4.5us floor regardless of arrive
// mechanism). Cost: float-atomic ordering -> absmax ~1e-5 instead of 0.
__global__ void __launch_bounds__(TPB) fused(
    const int* __restrict__ ct0, const int* __restrict__ cts,
    const int* __restrict__ y, const int* __restrict__ sk_y,
    const float* __restrict__ bias1,
    const float* __restrict__ bn1_g, const float* __restrict__ bn1_b,
    const float* __restrict__ bn1_m, const float* __restrict__ bn1_v,
    const float* __restrict__ conv2_w, const float* __restrict__ conv2_b,
    const float* __restrict__ bn2_g, const float* __restrict__ bn2_b,
    const float* __restrict__ bn2_m, const float* __restrict__ bn2_v,
    const float* __restrict__ conv3_w, const float* __restrict__ conv3_b,
    const float* __restrict__ bn3_g, const float* __restrict__ bn3_b,
    const float* __restrict__ bn3_m, const float* __restrict__ bn3_v,
    const float* __restrict__ fc1_w, const float* __restrict__ fc1_b,
    const float* __restrict__ fc2_w, const float* __restrict__ fc2_b,
    const int16_t* __restrict__ table,
    float* __restrict__ pooled, float* __restrict__ c3pre,
    float* __restrict__ out, unsigned* __restrict__ ctrs) {

    __shared__ union {
        float raw[392];                                          // A: 1.6 KB
        struct {                                                 // B: ~32.3 KB
            float s1p[16][16][16];   // conv2 input, halo-padded
            float w2[4][144];        // conv2 weights (4 oc)
            float co[4][196];        // conv2 output (pre-pool)
            float s2p[4][9][9];      // pooled s2 slice, halo-padded
            float w3s[64 * 36];      // conv3 weights [oc][4 ic][9]
        } b;
        struct {                                                 // CD: ~39.2 KB
            float w[16 * 576];       // fc1 slice (16 outputs)
            float s3[576];
            float h[16];
        } cd;
    } sm;

    const int bid = blockIdx.x;
    const int tid = threadIdx.x;

    // ---------------- Phase A: decrypt + bn1 + relu + pool(28->14) ---------
    // block = (k, b, half). Validated r6-r9 (~2.7us, absmax 0).
    {
        const int pair = bid >> 1, half = bid & 1;
        const int k = pair & 15, b = pair >> 4;
        const int* yrow = y + k * LLEN;
        int yv[LLEN];
#pragma unroll
        for (int i = 0; i < LLEN; i++) yv[i] = yrow[i];      // scalar loads
        const uint32_t sk = (uint32_t)sk_y[k];
        const float sc  = bn1_g[k] * rsqrtf(bn1_v[k] + 1e-5f);
        const float shf = (bias1[k] - bn1_m[k]) * sc + bn1_b[k];

        if (tid < 392) {
            const int j = half * 392 + tid;
            const int* crow = cts + ((b * NPATCH) + j) * LLEN;
            uint32_t c[LLEN];
#pragma unroll
            for (int i = 0; i < LLEN; i++) c[i] = (uint32_t)crow[i];

            uint32_t accp = 1u, accn = 1u;
#pragma unroll
            for (int bit = 5; bit >= 0; bit--) {
                accp = mmul(accp, accp);
                accn = mmul(accn, accn);
#pragma unroll
                for (int i = 0; i < LLEN; i++) {
                    int yi = yv[i];
                    int ay = (yi > 0) ? yi : -yi;
                    if ((ay >> bit) & 1) {
                        if (yi > 0) accp = mmul(accp, c[i]);
                        else        accn = mmul(accn, c[i]);
                    }
                }
            }

            uint32_t den = mmul(mpow((uint32_t)ct0[b * NPATCH + j], sk), accn);
            uint32_t val = mmul(accp, mpow(den, PRIME - 2u));  // const exp

            int ip = (int)table[val];              // guaranteed hit
            sm.raw[tid] = fmaxf(fmaf((float)ip, sc * 1e-4f, shf), 0.0f);
        }
        __syncthreads();
        if (tid < 98) {                            // pool 14x28 -> 7x14
            int pyl = tid / 14, px = tid % 14;
            const float* r0 = &sm.raw[(2 * pyl) * 28 + 2 * px];
            float m = fmaxf(fmaxf(r0[0], r0[1]), fmaxf(r0[28], r0[29]));
            cstore(&pooled[((b * KCH) + k) * 196 + (half * 7 + pyl) * 14 + px], m);
        }
    }
    arrive32(ctrs, bid);                           // -> 128

    // ---------------- Phase B (bid<32): conv2 + conv3 partial --------------
    if (bid < 32) {
        const int b = bid >> 3, base_oc = (bid & 7) * 4;

        // prep (input-independent) BEFORE the wait: overlaps A's tail
        for (int i = tid; i < 16 * 16 * 16; i += TPB)
            ((float*)sm.b.s1p)[i] = 0.0f;
        for (int i = tid; i < 4 * 81; i += TPB)
            ((float*)sm.b.s2p)[i] = 0.0f;
        if (tid < 576) sm.b.w2[tid / 144][tid % 144] =
            conv2_w[(base_oc + tid / 144) * 144 + tid % 144];
        for (int i = tid; i < 64 * 36; i += TPB) {  // w3 slice: [oc][4ic][9]
            int oc = i / 36, j = (i % 36) / 9, t = i % 9;
            sm.b.w3s[i] = conv3_w[(oc * 32 + base_oc + j) * 9 + t];
        }

        wait32(ctrs, 128);                          // ends with __syncthreads

        for (int i = tid; i < 16 * 196; i += TPB) {
            int ic = i / 196, pos = i % 196;
            sm.b.s1p[ic][pos / 14 + 1][pos % 14 + 1] =
                cload(&pooled[((b * KCH) + ic) * 196 + pos]);
        }
        __syncthreads();

        if (tid < 784) {                            // conv2: 4 oc x 196 pos
            int ocs = tid / 196, pos = tid % 196;
            int oh = pos / 14, ow = pos % 14;
            int oc = base_oc + ocs;
            float a0 = 0.0f, a1 = 0.0f, a2 = 0.0f;
#pragma unroll
            for (int ic = 0; ic < 16; ic++) {
                const float* wp = &sm.b.w2[ocs][ic * 9];
                const float* sp = &sm.b.s1p[ic][oh][ow];
                a0 = fmaf(sp[0],  wp[0], fmaf(sp[1],  wp[1], fmaf(sp[2],  wp[2], a0)));
                a1 = fmaf(sp[16], wp[3], fmaf(sp[17], wp[4], fmaf(sp[18], wp[5], a1)));
                a2 = fmaf(sp[32], wp[6], fmaf(sp[33], wp[7], fmaf(sp[34], wp[8], a2)));
            }
            float sc = bn2_g[oc] * rsqrtf(bn2_v[oc] + 1e-5f);
            float shf = bn2_b[oc] - bn2_m[oc] * sc;
            sm.b.co[ocs][pos] = fmaxf((a0 + a1 + a2 + conv2_b[oc]) * sc + shf, 0.0f);
        }
        __syncthreads();

        if (tid < 196) {                            // pool 14->7 into s2p
            int ocs = tid / 49, pp = tid % 49;
            int oh = pp / 7, ow = pp % 7;
            const float* c0 = &sm.b.co[ocs][(2 * oh) * 14 + 2 * ow];
            sm.b.s2p[ocs][oh + 1][ow + 1] =
                fmaxf(fmaxf(c0[0], c0[1]), fmaxf(c0[14], c0[15]));
        }
        __syncthreads();

        // conv3 partial: this block's 4 ic -> ALL 64 oc, atomicAdd to c3pre
        for (int i = tid; i < 64 * 49; i += TPB) {
            int oc = i / 49, pos = i % 49;
            int oh = pos / 7, ow = pos % 7;
            float a0 = 0.0f, a1 = 0.0f, a2 = 0.0f;
#pragma unroll
            for (int j = 0; j < 4; j++) {
                const float* wp = &sm.b.w3s[oc * 36 + j * 9];
                const float* sp = &sm.b.s2p[j][oh][ow];
                a0 = fmaf(sp[0],  wp[0], fmaf(sp[1],  wp[1], fmaf(sp[2],  wp[2], a0)));
                a1 = fmaf(sp[9],  wp[3], fmaf(sp[10], wp[4], fmaf(sp[11], wp[5], a1)));
                a2 = fmaf(sp[18], wp[6], fmaf(sp[19], wp[7], fmaf(sp[20], wp[8], a2)));
            }
            atomicAdd(&c3pre[(b * 64 + oc) * 49 + pos], a0 + a1 + a2);
        }
        arrive32(ctrs, bid);                        // -> 160
        return;
    }
    if (bid >= 64) return;

    // ---------------- Phase CD (bid in [32,64)): bn3+pool + fc1 + fc2 ------
    {
        const int bb = bid - 32;
        const int b = bb >> 3, og = bb & 7;         // 8 blocks/batch, 16 outs

        // prefetch fc1 slice (36.9 KB) BEFORE the wait: overlaps ALL of B
        {
            const float4* src = (const float4*)(fc1_w + og * 16 * 576);
            float4* dst = (float4*)sm.cd.w;
            for (int i = tid; i < 16 * 576 / 4; i += TPB) dst[i] = src[i];
        }

        wait32(ctrs, 160);                          // c3pre complete

        // bn3 + relu + pool(7->3), full batch map (redundant per block, tiny)
        if (tid < 576) {
            int oc = tid / 9, p = tid % 9;
            int oh = p / 3, ow = p % 3;
            const float* base = &c3pre[(b * 64 + oc) * 49];
            int idx = (2 * oh) * 7 + 2 * ow;
            float sc = bn3_g[oc] * rsqrtf(bn3_v[oc] + 1e-5f);
            float shf = bn3_b[oc] - bn3_m[oc] * sc;
            float cb = conv3_b[oc];
            float r0 = fmaxf((cload(base + idx)     + cb) * sc + shf, 0.0f);
            float r1 = fmaxf((cload(base + idx + 1) + cb) * sc + shf, 0.0f);
            float r2 = fmaxf((cload(base + idx + 7) + cb) * sc + shf, 0.0f);
            float r3 = fmaxf((cload(base + idx + 8) + cb) * sc + shf, 0.0f);
            sm.cd.s3[tid] = fmaxf(fmaxf(r0, r1), fmaxf(r2, r3));
        }
        __syncthreads();

        // fc1 + relu: 16 waves x 1 output
        const int wid = tid >> 6, lane = tid & 63;
        {
            int o = og * 16 + wid;
            const float* w = sm.cd.w + wid * 576;
            float acc = 0.0f;
#pragma unroll
            for (int jj = 0; jj < 9; jj++)          // lanes across 576
                acc = fmaf(sm.cd.s3[jj * 64 + lane], w[jj * 64 + lane], acc);
#pragma unroll
            for (int off = 32; off; off >>= 1) acc += __shfl_down(acc, off);
            if (lane == 0) sm.cd.h[wid] = fmaxf(acc + fc1_b[o], 0.0f);
        }
        __syncthreads();

        // fc2 partial: 16-term contribution per output, atomicAdd to out
        if (tid < 10) {
            float acc = (og == 0) ? fc2_b[tid] : 0.0f;
            const float* w = fc2_w + tid * 128 + og * 16;
#pragma unroll
            for (int j = 0; j < 16; j++) acc = fmaf(sm.cd.h[j], w[j], acc);
            atomicAdd(&out[b * 10 + tid], acc);
        }
    }
}

extern "C" void kernel_launch(void* const* d_in, const int* in_sizes, int n_in,
                              void* d_out, int out_size, void* d_ws, size_t ws_size,
                              hipStream_t stream) {
    const int*   ct0    = (const int*)d_in[0];
    const int*   cts    = (const int*)d_in[1];
    const int*   y      = (const int*)d_in[2];
    const int*   sk_y   = (const int*)d_in[3];
    const float* bias1  = (const float*)d_in[4];
    const float* bn1_g  = (const float*)d_in[5];
    const float* bn1_b  = (const float*)d_in[6];
    const float* bn1_m  = (const float*)d_in[7];
    const float* bn1_v  = (const float*)d_in[8];
    const float* conv2_w = (const float*)d_in[9];
    const float* conv2_b = (const float*)d_in[10];
    const float* bn2_g  = (const float*)d_in[11];
    const float* bn2_b  = (const float*)d_in[12];
    const float* bn2_m  = (const float*)d_in[13];
    const float* bn2_v  = (const float*)d_in[14];
    const float* conv3_w = (const float*)d_in[15];
    const float* conv3_b = (const float*)d_in[16];
    const float* bn3_g  = (const float*)d_in[17];
    const float* bn3_b  = (const float*)d_in[18];
    const float* bn3_m  = (const float*)d_in[19];
    const float* bn3_v  = (const float*)d_in[20];
    const float* fc1_w  = (const float*)d_in[21];
    const float* fc1_b  = (const float*)d_in[22];
    const float* fc2_w  = (const float*)d_in[23];
    const float* fc2_b  = (const float*)d_in[24];
    const int*   g_in   = (const int*)d_in[25];
    float* out = (float*)d_out;

    char* ws = (char*)d_ws;
    int16_t*  table = (int16_t*)ws;
    unsigned* ctrs  = (unsigned*)(ws + CTR_OFF);
    float* pooled = (float*)(ws + POOL_OFF);
    float* c3pre  = (float*)(ws + C3P_OFF);

    build_table<<<(TBLN + 255) / 256, 256, 0, stream>>>(g_in, table, ctrs, c3pre, out);

    fused<<<NBLK, TPB, 0, stream>>>(
        ct0, cts, y, sk_y, bias1, bn1_g, bn1_b, bn1_m, bn1_v,
        conv2_w, conv2_b, bn2_g, bn2_b, bn2_m, bn2_v,
        conv3_w, conv3_b, bn3_g, bn3_b, bn3_m, bn3_v,
        fc1_w, fc1_b, fc2_w, fc2_b, table, pooled, c3pre, out, ctrs);
}

// Round 11
// 131.064 us; speedup vs baseline: 1.6930x; 1.0105x over previous
//
#include <hip/hip_runtime.h>
#include <stdint.h>

#define PRIME 1000003u
#define NORD  1000002u
#define KCH   16
#define BATCH 4
#define NPATCH 784
#define LLEN  9
#define IPMAX 9000          // |<x,y>| <= 20*50*9
#define TBLN  (2*IPMAX+1)
#define NBLK  64            // fused grid (all co-resident; 64 < 256 CUs)
#define TPB   1024          // 16 waves

// Workspace offsets (bytes); ws is 256 MiB, we use ~2.2 MB.
#define CTR_OFF   2000064   // 32 counters, 64 B apart (2048 B)
#define C2P_OFF   2008256   // float c2pre [4][32][14][14] (100352 B) accumulator
#define C3P_OFF   2108608   // float c3pre [4][64][7][7]   (50176 B)  accumulator

// Barrett: M = floor(2^41/p) = 2199016; exact for t < 2^40 with one cond-sub.
__device__ __forceinline__ uint32_t mmul(uint32_t a, uint32_t b) {
    uint64_t t = (uint64_t)a * (uint64_t)b;
    uint32_t q = (uint32_t)((t * 2199016ull) >> 41);
    uint32_t r = (uint32_t)t - q * PRIME;
    return (r >= PRIME) ? r - PRIME : r;
}

__device__ __forceinline__ uint32_t mpow(uint32_t base, uint32_t exp) {
    uint32_t r = 1u, b = base;
    while (exp) {
        if (exp & 1u) r = mmul(r, b);
        b = mmul(b, b);
        exp >>= 1;
    }
    return r;
}

// ---- Fence-free cross-phase data access (validated r2-r10: absmax 0) -------
__device__ __forceinline__ void cstore(float* p, float v) {
    __hip_atomic_store(p, v, __ATOMIC_RELAXED, __HIP_MEMORY_SCOPE_AGENT);
}
__device__ __forceinline__ float cload(const float* p) {
    return __hip_atomic_load(p, __ATOMIC_RELAXED, __HIP_MEMORY_SCOPE_AGENT);
}

// ---- Grid barrier: 32-way split counters (r9/r10 mechanism) ----------------
__device__ __forceinline__ void arrive32(unsigned* ctrs, int bid) {
    __syncthreads();   // all block stores/atomics vmcnt-retired before the add
    if (threadIdx.x == 0)
        __hip_atomic_fetch_add(&ctrs[(bid & 31) * 16], 1u,
                               __ATOMIC_RELAXED, __HIP_MEMORY_SCOPE_AGENT);
}
__device__ __forceinline__ void wait32(unsigned* ctrs, unsigned target) {
    if (threadIdx.x == 0) {
        for (;;) {
            unsigned s = 0;
#pragma unroll
            for (int i = 0; i < 32; i++)
                s += __hip_atomic_load(&ctrs[i * 16],
                                       __ATOMIC_RELAXED, __HIP_MEMORY_SCOPE_AGENT);
            if (s >= target) break;
            __builtin_amdgcn_s_sleep(4);
        }
    }
    __syncthreads();
}

// ---------------- Kernel 1: dlog table + accumulator zeroing ----------------
// Grid covers 25088 threads (c2pre is the largest zero target). table write
// guarded by e<TBLN. ws/out re-poisoned between iterations; kernel boundary
// orders the zeroing before the fused kernel's atomics.
__global__ void build_table(const int* __restrict__ g_in, int16_t* __restrict__ table,
                            unsigned* __restrict__ ctrs, float* __restrict__ c2pre,
                            float* __restrict__ c3pre, float* __restrict__ out) {
    int e = blockIdx.x * blockDim.x + threadIdx.x;
    if (e < 32)
        __hip_atomic_store(&ctrs[e * 16], 0u, __ATOMIC_RELAXED, __HIP_MEMORY_SCOPE_AGENT);
    if (e < BATCH * 32 * 196) cstore(&c2pre[e], 0.0f);
    if (e < BATCH * 64 * 49)  cstore(&c3pre[e], 0.0f);
    if (e < BATCH * 10)       cstore(&out[e], 0.0f);
    if (e >= TBLN) return;
    int es = e - IPMAX;
    uint32_t exp = (es >= 0) ? (uint32_t)es : (uint32_t)(es + (int)NORD);
    table[mpow((uint32_t)g_in[0], exp)] = (int16_t)es;
}

// ---------------- Kernel 2: fused pipeline, TWO grid barriers ---------------
// 64 blocks x 1024. Phases (cumulative arrival targets):
//   A : decrypt+bn1+relu+pool (k,b full map) + conv2-PARTIAL
//       (own channel k -> all 32 oc) atomicAdd c2pre   all 64     -> 64
//   B': bias2+bn2+relu+pool (4 ic) + conv3-PARTIAL
//       (4 ic -> all 64 oc) atomicAdd c3pre            bid<32     -> 96
//   CD: bias3+bn3+relu+pool + fc1 (16 outs) + fc2-PARTIAL
//       atomicAdd out                                  bid in [32,64)
// conv2, conv3, fc2 are all linear in the sliced inputs -> every cross-slice
// mix is an atomic accumulator; only the two nonlinearities (bn2-relu,
// bn3-relu) need barriers. This is the minimum handoff count for this net.
// vs r10: conv2 moved from 32 post-barrier blocks to 64 phase-A blocks
// (+56K MAC/block, trivial), phase B shrinks ~3us -> ~1us, `pooled` gone.
__global__ void __launch_bounds__(TPB) fused(
    const int* __restrict__ ct0, const int* __restrict__ cts,
    const int* __restrict__ y, const int* __restrict__ sk_y,
    const float* __restrict__ bias1,
    const float* __restrict__ bn1_g, const float* __restrict__ bn1_b,
    const float* __restrict__ bn1_m, const float* __restrict__ bn1_v,
    const float* __restrict__ conv2_w, const float* __restrict__ conv2_b,
    const float* __restrict__ bn2_g, const float* __restrict__ bn2_b,
    const float* __restrict__ bn2_m, const float* __restrict__ bn2_v,
    const float* __restrict__ conv3_w, const float* __restrict__ conv3_b,
    const float* __restrict__ bn3_g, const float* __restrict__ bn3_b,
    const float* __restrict__ bn3_m, const float* __restrict__ bn3_v,
    const float* __restrict__ fc1_w, const float* __restrict__ fc1_b,
    const float* __restrict__ fc2_w, const float* __restrict__ fc2_b,
    const int16_t* __restrict__ table,
    float* __restrict__ c2pre, float* __restrict__ c3pre,
    float* __restrict__ out, unsigned* __restrict__ ctrs) {

    __shared__ union {
        struct { float raw[784]; float p1p[16][16]; float w2k[288]; } a;   // 5.3 KB
        struct { float s2p[4][9][9]; float w3s[64 * 36]; } b2;             // 10.5 KB
        struct { float w[16 * 576]; float s3[576]; float h[16]; } cd;      // 39.2 KB
    } sm;

    const int bid = blockIdx.x;
    const int tid = threadIdx.x;

    // ---------------- Phase A: decrypt+bn1+relu+pool + conv2 partial -------
    // block = (k, b): full 784-patch map (r3-validated shape).
    {
        const int k = bid & 15, b = bid >> 4;

        for (int i = tid; i < 256; i += TPB) ((float*)sm.a.p1p)[i] = 0.0f;
        if (tid < 288)                         // conv2 weights for channel k
            sm.a.w2k[tid] = conv2_w[(tid / 9) * 144 + k * 9 + (tid % 9)];

        const int* yrow = y + k * LLEN;
        int yv[LLEN];
#pragma unroll
        for (int i = 0; i < LLEN; i++) yv[i] = yrow[i];      // scalar loads
        const uint32_t sk = (uint32_t)sk_y[k];
        const float sc  = bn1_g[k] * rsqrtf(bn1_v[k] + 1e-5f);
        const float shf = (bias1[k] - bn1_m[k]) * sc + bn1_b[k];

        if (tid < NPATCH) {
            const int j = tid;
            const int* crow = cts + ((b * NPATCH) + j) * LLEN;
            uint32_t c[LLEN];
#pragma unroll
            for (int i = 0; i < LLEN; i++) c[i] = (uint32_t)crow[i];

            // Shamir: |y_i| <= 50 < 64 (6 bits). Branch conds block-uniform.
            uint32_t accp = 1u, accn = 1u;
#pragma unroll
            for (int bit = 5; bit >= 0; bit--) {
                accp = mmul(accp, accp);
                accn = mmul(accn, accn);
#pragma unroll
                for (int i = 0; i < LLEN; i++) {
                    int yi = yv[i];
                    int ay = (yi > 0) ? yi : -yi;
                    if ((ay >> bit) & 1) {
                        if (yi > 0) accp = mmul(accp, c[i]);
                        else        accn = mmul(accn, c[i]);
                    }
                }
            }

            uint32_t den = mmul(mpow((uint32_t)ct0[b * NPATCH + j], sk), accn);
            uint32_t val = mmul(accp, mpow(den, PRIME - 2u));  // const exp

            int ip = (int)table[val];              // guaranteed hit
            sm.a.raw[tid] = fmaxf(fmaf((float)ip, sc * 1e-4f, shf), 0.0f);
        }
        __syncthreads();
        if (tid < 196) {                           // pool 28x28 -> 14x14 (haloed)
            int pyl = tid / 14, px = tid % 14;
            const float* r0 = &sm.a.raw[(2 * pyl) * 28 + 2 * px];
            sm.a.p1p[pyl + 1][px + 1] =
                fmaxf(fmaxf(r0[0], r0[1]), fmaxf(r0[28], r0[29]));
        }
        __syncthreads();

        // conv2 partial: channel k -> ALL 32 oc, atomicAdd into c2pre
        for (int i = tid; i < 32 * 196; i += TPB) {
            int oc = i / 196, pos = i % 196;
            int oh = pos / 14, ow = pos % 14;
            const float* wp = &sm.a.w2k[oc * 9];
            const float* sp = &sm.a.p1p[oh][ow];
            float a0 = fmaf(sp[0],  wp[0], fmaf(sp[1],  wp[1], sp[2]  * wp[2]));
            float a1 = fmaf(sp[16], wp[3], fmaf(sp[17], wp[4], sp[18] * wp[5]));
            float a2 = fmaf(sp[32], wp[6], fmaf(sp[33], wp[7], sp[34] * wp[8]));
            atomicAdd(&c2pre[((b * 32 + oc) * 196) + pos], a0 + a1 + a2);
        }
    }
    arrive32(ctrs, bid);                           // -> 64

    // ---------------- Phase B' (bid<32): bn2+pool + conv3 partial ----------
    if (bid < 32) {
        const int b = bid >> 3, base_ic = (bid & 7) * 4;

        // prep (input-independent) BEFORE the wait: overlaps A's tail
        for (int i = tid; i < 4 * 81; i += TPB)
            ((float*)sm.b2.s2p)[i] = 0.0f;
        for (int i = tid; i < 64 * 36; i += TPB) {  // w3 slice [oc][4 ic][9]
            int oc = i / 36, j = (i % 36) / 9, t = i % 9;
            sm.b2.w3s[i] = conv3_w[(oc * 32 + base_ic + j) * 9 + t];
        }

        wait32(ctrs, 64);                           // c2pre complete

        if (tid < 196) {                            // bias2+bn2+relu+pool(14->7)
            int ics = tid / 49, pp = tid % 49;
            int oh = pp / 7, ow = pp % 7;
            int ic = base_ic + ics;
            float sc = bn2_g[ic] * rsqrtf(bn2_v[ic] + 1e-5f);
            float shf = bn2_b[ic] - bn2_m[ic] * sc;
            float cb = conv2_b[ic];
            const float* base = &c2pre[(b * 32 + ic) * 196];
            int idx = (2 * oh) * 14 + 2 * ow;
            float r0 = fmaxf((cload(base + idx)      + cb) * sc + shf, 0.0f);
            float r1 = fmaxf((cload(base + idx + 1)  + cb) * sc + shf, 0.0f);
            float r2 = fmaxf((cload(base + idx + 14) + cb) * sc + shf, 0.0f);
            float r3 = fmaxf((cload(base + idx + 15) + cb) * sc + shf, 0.0f);
            sm.b2.s2p[ics][oh + 1][ow + 1] = fmaxf(fmaxf(r0, r1), fmaxf(r2, r3));
        }
        __syncthreads();

        // conv3 partial: 4 ic -> ALL 64 oc, atomicAdd into c3pre (r10-valid)
        for (int i = tid; i < 64 * 49; i += TPB) {
            int oc = i / 49, pos = i % 49;
            int oh = pos / 7, ow = pos % 7;
            float a0 = 0.0f, a1 = 0.0f, a2 = 0.0f;
#pragma unroll
            for (int j = 0; j < 4; j++) {
                const float* wp = &sm.b2.w3s[oc * 36 + j * 9];
                const float* sp = &sm.b2.s2p[j][oh][ow];
                a0 = fmaf(sp[0],  wp[0], fmaf(sp[1],  wp[1], fmaf(sp[2],  wp[2], a0)));
                a1 = fmaf(sp[9],  wp[3], fmaf(sp[10], wp[4], fmaf(sp[11], wp[5], a1)));
                a2 = fmaf(sp[18], wp[6], fmaf(sp[19], wp[7], fmaf(sp[20], wp[8], a2)));
            }
            atomicAdd(&c3pre[(b * 64 + oc) * 49 + pos], a0 + a1 + a2);
        }
        arrive32(ctrs, bid);                        // -> 96
        return;
    }

    // ---------------- Phase CD (bid in [32,64)): bn3+pool + fc1 + fc2 ------
    {
        const int bb = bid - 32;
        const int b = bb >> 3, og = bb & 7;         // 8 blocks/batch, 16 outs

        // prefetch fc1 slice (36.9 KB) BEFORE the wait: overlaps ALL of B'
        {
            const float4* src = (const float4*)(fc1_w + og * 16 * 576);
            float4* dst = (float4*)sm.cd.w;
            for (int i = tid; i < 16 * 576 / 4; i += TPB) dst[i] = src[i];
        }

        wait32(ctrs, 96);                           // c3pre complete

        if (tid < 576) {                            // bias3+bn3+relu+pool(7->3)
            int oc = tid / 9, p = tid % 9;
            int oh = p / 3, ow = p % 3;
            const float* base = &c3pre[(b * 64 + oc) * 49];
            int idx = (2 * oh) * 7 + 2 * ow;
            float sc = bn3_g[oc] * rsqrtf(bn3_v[oc] + 1e-5f);
            float shf = bn3_b[oc] - bn3_m[oc] * sc;
            float cb = conv3_b[oc];
            float r0 = fmaxf((cload(base + idx)     + cb) * sc + shf, 0.0f);
            float r1 = fmaxf((cload(base + idx + 1) + cb) * sc + shf, 0.0f);
            float r2 = fmaxf((cload(base + idx + 7) + cb) * sc + shf, 0.0f);
            float r3 = fmaxf((cload(base + idx + 8) + cb) * sc + shf, 0.0f);
            sm.cd.s3[tid] = fmaxf(fmaxf(r0, r1), fmaxf(r2, r3));
        }
        __syncthreads();

        // fc1 + relu: 16 waves x 1 output
        const int wid = tid >> 6, lane = tid & 63;
        {
            int o = og * 16 + wid;
            const float* w = sm.cd.w + wid * 576;
            float acc = 0.0f;
#pragma unroll
            for (int jj = 0; jj < 9; jj++)          // lanes across 576
                acc = fmaf(sm.cd.s3[jj * 64 + lane], w[jj * 64 + lane], acc);
#pragma unroll
            for (int off = 32; off; off >>= 1) acc += __shfl_down(acc, off);
            if (lane == 0) sm.cd.h[wid] = fmaxf(acc + fc1_b[o], 0.0f);
        }
        __syncthreads();

        // fc2 partial: 16-term contribution per output, atomicAdd to out
        if (tid < 10) {
            float acc = (og == 0) ? fc2_b[tid] : 0.0f;
            const float* w = fc2_w + tid * 128 + og * 16;
#pragma unroll
            for (int j = 0; j < 16; j++) acc = fmaf(sm.cd.h[j], w[j], acc);
            atomicAdd(&out[b * 10 + tid], acc);
        }
    }
}

extern "C" void kernel_launch(void* const* d_in, const int* in_sizes, int n_in,
                              void* d_out, int out_size, void* d_ws, size_t ws_size,
                              hipStream_t stream) {
    const int*   ct0    = (const int*)d_in[0];
    const int*   cts    = (const int*)d_in[1];
    const int*   y      = (const int*)d_in[2];
    const int*   sk_y   = (const int*)d_in[3];
    const float* bias1  = (const float*)d_in[4];
    const float* bn1_g  = (const float*)d_in[5];
    const float* bn1_b  = (const float*)d_in[6];
    const float* bn1_m  = (const float*)d_in[7];
    const float* bn1_v  = (const float*)d_in[8];
    const float* conv2_w = (const float*)d_in[9];
    const float* conv2_b = (const float*)d_in[10];
    const float* bn2_g  = (const float*)d_in[11];
    const float* bn2_b  = (const float*)d_in[12];
    const float* bn2_m  = (const float*)d_in[13];
    const float* bn2_v  = (const float*)d_in[14];
    const float* conv3_w = (const float*)d_in[15];
    const float* conv3_b = (const float*)d_in[16];
    const float* bn3_g  = (const float*)d_in[17];
    const float* bn3_b  = (const float*)d_in[18];
    const float* bn3_m  = (const float*)d_in[19];
    const float* bn3_v  = (const float*)d_in[20];
    const float* fc1_w  = (const float*)d_in[21];
    const float* fc1_b  = (const float*)d_in[22];
    const float* fc2_w  = (const float*)d_in[23];
    const float* fc2_b  = (const float*)d_in[24];
    const int*   g_in   = (const int*)d_in[25];
    float* out = (float*)d_out;

    char* ws = (char*)d_ws;
    int16_t*  table = (int16_t*)ws;
    unsigned* ctrs  = (unsigned*)(ws + CTR_OFF);
    float* c2pre  = (float*)(ws + C2P_OFF);
    float* c3pre  = (float*)(ws + C3P_OFF);

    // grid covers max(TBLN, 25088) threads for table + accumulator zeroing
    build_table<<<(BATCH * 32 * 196 + 255) / 256, 256, 0, stream>>>(
        g_in, table, ctrs, c2pre, c3pre, out);

    fused<<<NBLK, TPB, 0, stream>>>(
        ct0, cts, y, sk_y, bias1, bn1_g, bn1_b, bn1_m, bn1_v,
        conv2_w, conv2_b, bn2_g, bn2_b, bn2_m, bn2_v,
        conv3_w, conv3_b, bn3_g, bn3_b, bn3_m, bn3_v,
        fc1_w, fc1_b, fc2_w, fc2_b, table, c2pre, c3pre, out, ctrs);
}